// Round 10
// baseline (344.612 us; speedup 1.0000x reference)
//
#include <hip/hip_runtime.h>
#include <math.h>

// B=1, L=256, DP=128, DB=128, H=8, DH=32, H*DH=256
// bf16 MFMA 16x16x32. Q/K/G use a 4-row-tiled layout X4[(p>>2)][n][p&3];
// V projection stores D-fragments directly into Vtb (row axis j=r is the
// fast axis -> 8B packed stores, no LDS anywhere in the projections).
// NO atomics / cross-kernel RMW anywhere: bit-deterministic across replays.
//
// Fragment layouts (HW-verified):
//   A-frag: lane holds A[m=lane&15][k=(lane>>4)*8+j], j=0..7 (16B)
//   B-frag: lane holds B[k=(lane>>4)*8+j][n=lane&15]
//   D:      lane holds D[row=(lane>>4)*4+reg][col=lane&15]
//
// Workspace (byte offsets):
//   PNb  u16 [65536][128]     @ 0            16,777,216   LN(pair), row p=r*256+sc
//   Qr4  u16 tiled [16384][256][4] @ 16777216 33,554,432  (p>>2, n, p&3), p=(i,sc)
//   Kr4  u16 tiled             @ 50331648    33,554,432
//   Vtb  u16 [8][8192][256]   @ 83886080     33,554,432   [h][k*32+d][j]
//   G2   u16 tiled             @ 117440512   33,554,432   p = r*256+sc (= kslot*256+i)
//   GOb  u16 [65536][256]     @ 150994944    33,554,432   row = i*256+k
//   Bp   f32 [8][256][256]    @ 184549376     2,097,152
//   Ab   u16 [8][256][256]    @ 186646528     1,048,576
//   Wtb  u16 [4][256][128]    @ 187695104       262,144   W{q,k,v,g}^T [n][k]
//   Wotb u16 [128][256]       @ 187957248        65,536   Wo^T [c][e]
//   Lg2  f32 [16][8][256][256]@ 188022784    33,554,432   split-K logit slices
// total 221,577,216 B

typedef unsigned short u16;
typedef __attribute__((ext_vector_type(8))) short short8;
typedef __attribute__((ext_vector_type(4))) short short4v;
typedef __attribute__((ext_vector_type(4))) float float4v;

__device__ __forceinline__ u16 f2bf(float f) {
  unsigned int u = __float_as_uint(f);
  u += 0x7FFFu + ((u >> 16) & 1u);
  return (u16)(u >> 16);
}
__device__ __forceinline__ float bf2f(u16 h) {
  return __uint_as_float(((unsigned int)h) << 16);
}

// ---------------- K1: LayerNorm(pair) -> PNb (bf16) ----------------
__global__ __launch_bounds__(256) void k_ln(const float* __restrict__ x,
                                            const float* __restrict__ g,
                                            const float* __restrict__ b,
                                            u16* __restrict__ y) {
  int p = blockIdx.x * 4 + (threadIdx.x >> 6);
  int lane = threadIdx.x & 63;
  float2 xv = *(const float2*)(x + (size_t)p * 128 + lane * 2);
  float x0 = xv.x, x1 = xv.y;
  float s = x0 + x1, ss = x0 * x0 + x1 * x1;
#pragma unroll
  for (int off = 32; off; off >>= 1) {
    s += __shfl_xor(s, off);
    ss += __shfl_xor(ss, off);
  }
  float m = s * (1.0f / 128.0f);
  float v = ss * (1.0f / 128.0f) - m * m;
  float inv = rsqrtf(v + 1e-5f);
  float2 gv = *(const float2*)(g + lane * 2);
  float2 bv = *(const float2*)(b + lane * 2);
  float y0 = (x0 - m) * inv * gv.x + bv.x;
  float y1 = (x1 - m) * inv * gv.y + bv.y;
  unsigned int pk = (unsigned int)f2bf(y0) | ((unsigned int)f2bf(y1) << 16);
  *(unsigned int*)(y + (size_t)p * 128 + lane * 2) = pk;
}

// ---------------- K2: LayerNorm(bias) -> Bp (fp32) ----------------
__global__ __launch_bounds__(256) void k_lnbias_bproj(const float* __restrict__ x,
                                                      const float* __restrict__ g,
                                                      const float* __restrict__ b,
                                                      const float* __restrict__ Wb,
                                                      float* __restrict__ Bp) {
  const int t = threadIdx.x;
  const int row = t >> 3, h = t & 7;
  const int p = blockIdx.x * 32 + row;
  const int r = p >> 8, sc = p & 255;
  const float* rp = x + (size_t)p * 128 + h * 16;
  float4 xv[4];
#pragma unroll
  for (int i = 0; i < 4; ++i) xv[i] = ((const float4*)rp)[i];
  float s = 0.f, ss = 0.f;
#pragma unroll
  for (int i = 0; i < 4; ++i) {
    s += (xv[i].x + xv[i].y) + (xv[i].z + xv[i].w);
    ss += (xv[i].x * xv[i].x + xv[i].y * xv[i].y) + (xv[i].z * xv[i].z + xv[i].w * xv[i].w);
  }
#pragma unroll
  for (int off = 1; off <= 4; off <<= 1) {
    s += __shfl_xor(s, off);
    ss += __shfl_xor(ss, off);
  }
  float m = s * (1.0f / 128.0f);
  float var = ss * (1.0f / 128.0f) - m * m;
  float inv = rsqrtf(var + 1e-5f);
  float part[8];
#pragma unroll
  for (int hh = 0; hh < 8; ++hh) part[hh] = 0.f;
  const float4* g4 = (const float4*)(g + h * 16);
  const float4* b4 = (const float4*)(b + h * 16);
#pragma unroll
  for (int i4 = 0; i4 < 4; ++i4) {
    float4 gv = g4[i4], bv = b4[i4];
    float xs[4] = {xv[i4].x, xv[i4].y, xv[i4].z, xv[i4].w};
    float gs[4] = {gv.x, gv.y, gv.z, gv.w};
    float bs[4] = {bv.x, bv.y, bv.z, bv.w};
#pragma unroll
    for (int q = 0; q < 4; ++q) {
      int k = h * 16 + i4 * 4 + q;
      float xn = (xs[q] - m) * inv * gs[q] + bs[q];
      float4 w0 = *(const float4*)(Wb + k * 8);
      float4 w1 = *(const float4*)(Wb + k * 8 + 4);
      part[0] += xn * w0.x;
      part[1] += xn * w0.y;
      part[2] += xn * w0.z;
      part[3] += xn * w0.w;
      part[4] += xn * w1.x;
      part[5] += xn * w1.y;
      part[6] += xn * w1.z;
      part[7] += xn * w1.w;
    }
  }
#pragma unroll
  for (int off = 1; off <= 4; off <<= 1) {
#pragma unroll
    for (int hh = 0; hh < 8; ++hh) part[hh] += __shfl_xor(part[hh], off);
  }
  float val = (h == 0) ? part[0]
            : (h == 1) ? part[1]
            : (h == 2) ? part[2]
            : (h == 3) ? part[3]
            : (h == 4) ? part[4]
            : (h == 5) ? part[5]
            : (h == 6) ? part[6]
                       : part[7];
  Bp[(size_t)h * 65536 + (size_t)sc * 256 + r] = val;
}

// ---------------- K3: weight convert/transpose to bf16 ----------------
__global__ __launch_bounds__(256) void k_wcvt(const float* __restrict__ Wq,
                                              const float* __restrict__ Wk,
                                              const float* __restrict__ Wv,
                                              const float* __restrict__ Wg,
                                              const float* __restrict__ Wo,
                                              u16* __restrict__ Wtb,
                                              u16* __restrict__ Wotb) {
  int idx = blockIdx.x * 256 + threadIdx.x;
  if (idx < 131072) {
    int w = idx >> 15, r = idx & 32767;
    int n = r >> 7, k = r & 127;  // out [n][k]
    const float* W = (w == 0) ? Wq : (w == 1) ? Wk : (w == 2) ? Wv : Wg;
    Wtb[(size_t)w * 32768 + n * 128 + k] = f2bf(W[k * 256 + n]);
  } else {
    int r = idx - 131072;  // Wo [256 e][128 c] -> Wotb[c][e]
    int c = r >> 8, e = r & 255;
    Wotb[c * 256 + e] = f2bf(Wo[e * 128 + c]);
  }
}

// ---------------- K4 v4: Q/K/gate projections, tiled packed stores ----------
// grid (256 stripes of 256 rows, 4 col-quarters, 3 weights). No LDS, no
// barriers, no unroll (r9 post-mortem: unroll-2 raised VGPR+L2 sectors, -40%).
__global__ __launch_bounds__(256) void k_proj_qkg(const u16* __restrict__ PNb,
                                                  const u16* __restrict__ Wtb,
                                                  const float* __restrict__ bg,
                                                  u16* __restrict__ Qr4,
                                                  u16* __restrict__ Kr4,
                                                  u16* __restrict__ G2) {
  const int t = threadIdx.x;
  const int wid = t >> 6, lane = t & 63;
  const int mrow = lane & 15, quad = lane >> 4;
  const int stripe = blockIdx.x;
  const int n0 = blockIdx.y * 64;
  const int wsel3 = blockIdx.z;  // 0:Q 1:K 2:G
  const int wsel = (wsel3 == 2) ? 3 : wsel3;
  const u16* Wt = Wtb + (size_t)wsel * 32768;
  u16* dst = (wsel3 == 0) ? Qr4 : (wsel3 == 1) ? Kr4 : G2;

  short8 bfr[4][4];
#pragma unroll
  for (int nt = 0; nt < 4; ++nt)
#pragma unroll
    for (int kk = 0; kk < 4; ++kk)
      bfr[nt][kk] = *(const short8*)(Wt + (size_t)(n0 + nt * 16 + mrow) * 128 + kk * 32 + quad * 8);

  float bgv[4];
#pragma unroll
  for (int nt = 0; nt < 4; ++nt) bgv[nt] = bg[n0 + nt * 16 + mrow];

  for (int it = 0; it < 2; ++it) {
    const int pw = stripe * 256 + it * 128 + wid * 32;
    short8 afr[2][4];
#pragma unroll
    for (int mt = 0; mt < 2; ++mt)
#pragma unroll
      for (int kk = 0; kk < 4; ++kk)
        afr[mt][kk] =
            *(const short8*)(PNb + (size_t)(pw + mt * 16 + mrow) * 128 + kk * 32 + quad * 8);
    float4v acc[2][4];
#pragma unroll
    for (int mt = 0; mt < 2; ++mt)
#pragma unroll
      for (int nt = 0; nt < 4; ++nt) acc[mt][nt] = (float4v){0.f, 0.f, 0.f, 0.f};
#pragma unroll
    for (int kk = 0; kk < 4; ++kk)
#pragma unroll
      for (int mt = 0; mt < 2; ++mt)
#pragma unroll
        for (int nt = 0; nt < 4; ++nt)
          acc[mt][nt] = __builtin_amdgcn_mfma_f32_16x16x32_bf16(afr[mt][kk], bfr[nt][kk],
                                                                acc[mt][nt], 0, 0, 0);
#pragma unroll
    for (int mt = 0; mt < 2; ++mt) {
      const int prow4 = ((pw + mt * 16) >> 2) + quad;  // p>>2 for this lane's 4 rows
#pragma unroll
      for (int nt = 0; nt < 4; ++nt) {
        const int n = n0 + nt * 16 + mrow;
        short4v pk;
#pragma unroll
        for (int reg = 0; reg < 4; ++reg) {
          float v = acc[mt][nt][reg];
          if (wsel3 == 0) v *= 0.17677669529663687f;
          else if (wsel3 == 1) v *= 0.0625f;
          else v = 1.f / (1.f + expf(-(v + bgv[nt])));
          pk[reg] = (short)f2bf(v);
        }
        *(short4v*)(dst + ((size_t)prow4 * 256 + n) * 4) = pk;
      }
    }
  }
}

// ---------------- K5 v2: V projection, direct packed stores into Vtb --------
// grid (256 sc, 4 n-quarters). Output rows are r = j (Vtb fast axis), so the
// D-frag's 4 consecutive rows pack into one 8B store. No LDS, no barriers.
__global__ __launch_bounds__(256) void k_projv(const u16* __restrict__ PNb,
                                               const u16* __restrict__ Wtb,
                                               u16* __restrict__ Vtb) {
  const int t = threadIdx.x;
  const int wid = t >> 6, lane = t & 63;
  const int mrow = lane & 15, quad = lane >> 4;
  const int sc = blockIdx.x;
  const int n0 = blockIdx.y * 64;
  const u16* Wt = Wtb + (size_t)2 * 32768;

  short8 bfr[4][4];
#pragma unroll
  for (int nt = 0; nt < 4; ++nt)
#pragma unroll
    for (int kk = 0; kk < 4; ++kk)
      bfr[nt][kk] = *(const short8*)(Wt + (size_t)(n0 + nt * 16 + mrow) * 128 + kk * 32 + quad * 8);

  for (int it = 0; it < 2; ++it) {
    const int rbase = it * 128 + wid * 32;
    short8 afr[2][4];
#pragma unroll
    for (int mt = 0; mt < 2; ++mt)
#pragma unroll
      for (int kk = 0; kk < 4; ++kk)
        afr[mt][kk] = *(const short8*)(PNb + ((size_t)(rbase + mt * 16 + mrow) * 256 + sc) * 128 +
                                       kk * 32 + quad * 8);
    float4v acc[2][4];
#pragma unroll
    for (int mt = 0; mt < 2; ++mt)
#pragma unroll
      for (int nt = 0; nt < 4; ++nt) acc[mt][nt] = (float4v){0.f, 0.f, 0.f, 0.f};
#pragma unroll
    for (int kk = 0; kk < 4; ++kk)
#pragma unroll
      for (int mt = 0; mt < 2; ++mt)
#pragma unroll
        for (int nt = 0; nt < 4; ++nt)
          acc[mt][nt] = __builtin_amdgcn_mfma_f32_16x16x32_bf16(afr[mt][kk], bfr[nt][kk],
                                                                acc[mt][nt], 0, 0, 0);
#pragma unroll
    for (int mt = 0; mt < 2; ++mt) {
      const int j0 = rbase + mt * 16 + quad * 4;  // 4 consecutive j
#pragma unroll
      for (int nt = 0; nt < 4; ++nt) {
        const int n = n0 + nt * 16 + mrow;
        const int h = n >> 5, d = n & 31;
        short4v pk;
#pragma unroll
        for (int reg = 0; reg < 4; ++reg) pk[reg] = (short)f2bf(acc[mt][nt][reg]);
        *(short4v*)(Vtb + (size_t)h * 2097152 + (size_t)(sc * 32 + d) * 256 + j0) = pk;
      }
    }
  }
}

// ---------------- K6 v2: logits (MFMA) from tiled Qr4/Kr4 ----------------
__global__ __launch_bounds__(256) void k_logits_mfma(const u16* __restrict__ Qr4,
                                                     const u16* __restrict__ Kr4,
                                                     float* __restrict__ Lg2) {
  __shared__ u16 Qs[128 * 72];
  __shared__ u16 Ks[128 * 72];
  const int t = threadIdx.x;
  const int wid = t >> 6, lane = t & 63;
  const int mrow = lane & 15, quad = lane >> 4;
  const int i0 = (blockIdx.x >> 1) * 128, j0 = (blockIdx.x & 1) * 128;
  const int h = blockIdx.y;
  const int z = blockIdx.z;  // 0..15
  const int wi = wid >> 1, wj = wid & 1;
  float4v acc[4][4];
#pragma unroll
  for (int a = 0; a < 4; ++a)
#pragma unroll
    for (int bq = 0; bq < 4; ++bq) acc[a][bq] = (float4v){0.f, 0.f, 0.f, 0.f};

  for (int g = 0; g < 4; ++g) {
    const int sc4 = z * 4 + g;
    for (int sub = 0; sub < 2; ++sub) {
      __syncthreads();
#pragma unroll
      for (int itq = 0; itq < 4; ++itq) {
        int u = itq * 256 + t;
        int i_loc = u >> 3, c16 = sub * 8 + (u & 7);
        size_t qoff = ((size_t)((i0 + i_loc) * 64 + sc4) * 256 + h * 32 + c16 * 2) * 4;
        *(short8*)&Qs[i_loc * 72 + (u & 7) * 8] = *(const short8*)(Qr4 + qoff);
        size_t koff = ((size_t)((j0 + i_loc) * 64 + sc4) * 256 + h * 32 + c16 * 2) * 4;
        *(short8*)&Ks[i_loc * 72 + (u & 7) * 8] = *(const short8*)(Kr4 + koff);
      }
      __syncthreads();
#pragma unroll
      for (int kk = 0; kk < 2; ++kk) {
        short8 afr[4], bfr[4];
#pragma unroll
        for (int mt = 0; mt < 4; ++mt)
          afr[mt] = *(const short8*)&Qs[(wi * 64 + mt * 16 + mrow) * 72 + kk * 32 + quad * 8];
#pragma unroll
        for (int nn = 0; nn < 4; ++nn)
          bfr[nn] = *(const short8*)&Ks[(wj * 64 + nn * 16 + mrow) * 72 + kk * 32 + quad * 8];
#pragma unroll
        for (int mt = 0; mt < 4; ++mt)
#pragma unroll
          for (int nn = 0; nn < 4; ++nn)
            acc[mt][nn] =
                __builtin_amdgcn_mfma_f32_16x16x32_bf16(afr[mt], bfr[nn], acc[mt][nn], 0, 0, 0);
      }
    }
  }
  float* slab = Lg2 + ((size_t)z * 8 + h) * 65536;
#pragma unroll
  for (int mt = 0; mt < 4; ++mt)
#pragma unroll
    for (int nn = 0; nn < 4; ++nn) {
      int j = j0 + wj * 64 + nn * 16 + mrow;
#pragma unroll
      for (int reg = 0; reg < 4; ++reg) {
        int i = i0 + wi * 64 + mt * 16 + quad * 4 + reg;
        slab[(size_t)i * 256 + j] = acc[mt][nn][reg];
      }
    }
}

// ---------------- K7: masked softmax over j (sum Bp + 16 slabs) -> Ab --------
__global__ __launch_bounds__(256) void k_softmax(const float* __restrict__ Bp,
                                                 const float* __restrict__ Lg2,
                                                 const int* __restrict__ mask,
                                                 u16* __restrict__ Ab) {
  const int i = blockIdx.x, h = blockIdx.y;
  const int j = threadIdx.x;
  __shared__ float red[4], red2[4];
  const size_t off = (size_t)h * 65536 + (size_t)i * 256 + j;
  float x = Bp[off];
#pragma unroll
  for (int z = 0; z < 16; ++z) x += Lg2[(size_t)z * 524288 + off];
  bool mi = (mask[i] == 0);
  if (mi || (mask[j] == 0)) x = -1e9f;
  float mx = x;
#pragma unroll
  for (int off2 = 32; off2; off2 >>= 1) mx = fmaxf(mx, __shfl_xor(mx, off2));
  int wave = j >> 6;
  if ((j & 63) == 0) red[wave] = mx;
  __syncthreads();
  mx = fmaxf(fmaxf(red[0], red[1]), fmaxf(red[2], red[3]));
  float e = expf(x - mx);
  float sm = e;
#pragma unroll
  for (int off2 = 32; off2; off2 >>= 1) sm += __shfl_xor(sm, off2);
  if ((j & 63) == 0) red2[wave] = sm;
  __syncthreads();
  sm = red2[0] + red2[1] + red2[2] + red2[3];
  Ab[off] = f2bf(e / sm);
}

// ---------------- K8: AV (MFMA) + gate (b64 tiled loads) -> GOb --------------
__global__ __launch_bounds__(256) void k_av_mfma(const u16* __restrict__ Ab,
                                                 const u16* __restrict__ Vtb,
                                                 const u16* __restrict__ G2,
                                                 u16* __restrict__ GOb) {
  __shared__ u16 As[64 * 264];
  const int t = threadIdx.x;
  const int wid = t >> 6, lane = t & 63;
  const int mrow = lane & 15, quad = lane >> 4;
  const int h = blockIdx.z;
  const int i0 = blockIdx.y * 64;
  const u16* ag = Ab + (size_t)h * 65536 + (size_t)i0 * 256;
#pragma unroll
  for (int u = 0; u < 8; ++u) {
    int id = u * 256 + t;
    int rr = id >> 5, c8 = (id & 31) * 8;
    *(short8*)&As[rr * 264 + c8] = *(const short8*)(ag + (size_t)rr * 256 + c8);
  }
  __syncthreads();
  const u16* vg = Vtb + (size_t)h * 2097152;
  for (int nt4 = 0; nt4 < 4; ++nt4) {
    const int nbase = blockIdx.x * 1024 + wid * 256 + nt4 * 64;
    float4v acc[4][4];
#pragma unroll
    for (int a = 0; a < 4; ++a)
#pragma unroll
      for (int bq = 0; bq < 4; ++bq) acc[a][bq] = (float4v){0.f, 0.f, 0.f, 0.f};
#pragma unroll
    for (int kk = 0; kk < 8; ++kk) {
      short8 afr[4], bfr[4];
#pragma unroll
      for (int mt = 0; mt < 4; ++mt)
        afr[mt] = *(const short8*)&As[(mt * 16 + mrow) * 264 + kk * 32 + quad * 8];
#pragma unroll
      for (int nn = 0; nn < 4; ++nn)
        bfr[nn] = *(const short8*)(vg + (size_t)(nbase + nn * 16 + mrow) * 256 + kk * 32 + quad * 8);
#pragma unroll
      for (int mt = 0; mt < 4; ++mt)
#pragma unroll
        for (int nn = 0; nn < 4; ++nn)
          acc[mt][nn] = __builtin_amdgcn_mfma_f32_16x16x32_bf16(afr[mt], bfr[nn], acc[mt][nn], 0, 0, 0);
    }
#pragma unroll
    for (int mt = 0; mt < 4; ++mt)
#pragma unroll
      for (int nn = 0; nn < 4; ++nn) {
        const int kslot = (nbase + nn * 16) >> 5;
        const int d = (nn & 1) * 16 + mrow;
        const int e = h * 32 + d;
        const int p4 = kslot * 64 + ((i0 + mt * 16) >> 2) + quad;
        short4v g4 = *(const short4v*)(G2 + ((size_t)p4 * 256 + e) * 4);
#pragma unroll
        for (int reg = 0; reg < 4; ++reg) {
          int i = i0 + mt * 16 + quad * 4 + reg;
          size_t idx = ((size_t)i * 256 + kslot) * 256 + e;
          float gv = bf2f((u16)g4[reg]);
          GOb[idx] = f2bf(acc[mt][nn][reg] * gv);
        }
      }
  }
}

// ---------------- K9: output proj (MFMA) + bias + transpose + mask ----------------
__global__ __launch_bounds__(256) void k_out_mfma(const u16* __restrict__ GOb,
                                                  const u16* __restrict__ Wotb,
                                                  const float* __restrict__ bo,
                                                  const int* __restrict__ mask,
                                                  float* __restrict__ out) {
  const int wid = threadIdx.x >> 6, lane = threadIdx.x & 63;
  const int mrow = lane & 15, quad = lane >> 4;
  const int m0 = blockIdx.x * 128 + wid * 32;
  short8 afr[2][8];
#pragma unroll
  for (int mt = 0; mt < 2; ++mt) {
    const u16* ar = GOb + (size_t)(m0 + mt * 16 + mrow) * 256 + quad * 8;
#pragma unroll
    for (int kk = 0; kk < 8; ++kk) afr[mt][kk] = *(const short8*)(ar + kk * 32);
  }
  for (int nt = 0; nt < 8; ++nt) {
    float4v acc[2];
    acc[0] = (float4v){0.f, 0.f, 0.f, 0.f};
    acc[1] = (float4v){0.f, 0.f, 0.f, 0.f};
    const u16* br = Wotb + (size_t)(nt * 16 + mrow) * 256 + quad * 8;
#pragma unroll
    for (int kk = 0; kk < 8; ++kk) {
      short8 bfr = *(const short8*)(br + kk * 32);
#pragma unroll
      for (int mt = 0; mt < 2; ++mt)
        acc[mt] = __builtin_amdgcn_mfma_f32_16x16x32_bf16(afr[mt][kk], bfr, acc[mt], 0, 0, 0);
    }
    const int c = nt * 16 + mrow;
    float bov = bo[c];
#pragma unroll
    for (int mt = 0; mt < 2; ++mt) {
#pragma unroll
      for (int reg = 0; reg < 4; ++reg) {
        int m = m0 + mt * 16 + quad * 4 + reg;  // = i*256 + k
        int i = m >> 8, kq = m & 255;
        float v = acc[mt][reg] + bov;
        bool z = (mask[i] == 0) || (mask[kq] == 0);
        out[((size_t)kq * 256 + i) * 128 + c] = z ? 0.f : v;
      }
    }
  }
}

extern "C" void kernel_launch(void* const* d_in, const int* in_sizes, int n_in,
                              void* d_out, int out_size, void* d_ws, size_t ws_size,
                              hipStream_t stream) {
  const float* pair = (const float*)d_in[0];
  const float* bias = (const float*)d_in[1];
  const int* mask = (const int*)d_in[2];
  const float* g_pair = (const float*)d_in[3];
  const float* b_pair = (const float*)d_in[4];
  const float* g_bias = (const float*)d_in[5];
  const float* b_bias = (const float*)d_in[6];
  const float* Wq = (const float*)d_in[7];
  const float* Wk = (const float*)d_in[8];
  const float* Wv = (const float*)d_in[9];
  const float* Wb = (const float*)d_in[10];
  const float* Wg = (const float*)d_in[11];
  const float* bg = (const float*)d_in[12];
  const float* Wo = (const float*)d_in[13];
  const float* bo = (const float*)d_in[14];
  float* out = (float*)d_out;
  char* ws = (char*)d_ws;

  u16* PNb = (u16*)(ws + 0);
  u16* Qr4 = (u16*)(ws + 16777216);
  u16* Kr4 = (u16*)(ws + 50331648);
  u16* Vtb = (u16*)(ws + 83886080);
  u16* G2 = (u16*)(ws + 117440512);
  u16* GOb = (u16*)(ws + 150994944);
  float* Bp = (float*)(ws + 184549376);
  u16* Ab = (u16*)(ws + 186646528);
  u16* Wtb = (u16*)(ws + 187695104);
  u16* Wotb = (u16*)(ws + 187957248);
  float* Lg2 = (float*)(ws + 188022784);

  k_ln<<<16384, 256, 0, stream>>>(pair, g_pair, b_pair, PNb);
  k_wcvt<<<640, 256, 0, stream>>>(Wq, Wk, Wv, Wg, Wo, Wtb, Wotb);
  k_lnbias_bproj<<<2048, 256, 0, stream>>>(bias, g_bias, b_bias, Wb, Bp);
  k_proj_qkg<<<dim3(256, 4, 3), 256, 0, stream>>>(PNb, Wtb, bg, Qr4, Kr4, G2);
  k_projv<<<dim3(256, 4), 256, 0, stream>>>(PNb, Wtb, Vtb);
  k_logits_mfma<<<dim3(4, 8, 16), 256, 0, stream>>>(Qr4, Kr4, Lg2);
  k_softmax<<<dim3(256, 8), 256, 0, stream>>>(Bp, Lg2, mask, Ab);
  k_av_mfma<<<dim3(8, 4, 8), 256, 0, stream>>>(Ab, Vtb, G2, GOb);
  k_out_mfma<<<512, 256, 0, stream>>>(GOb, Wotb, bo, mask, out);
}

// Round 11
// 329.159 us; speedup vs baseline: 1.0469x; 1.0469x over previous
//
#include <hip/hip_runtime.h>
#include <math.h>

// B=1, L=256, DP=128, DB=128, H=8, DH=32, H*DH=256
// bf16 MFMA 16x16x32. Q/K/G use a 4-row-tiled layout X4[(p>>2)][n][p&3];
// V projection stores D-fragments directly into Vtb (row axis j=r is the
// fast axis -> 8B packed stores, no LDS anywhere in the projections).
// NO atomics / cross-kernel RMW anywhere: bit-deterministic across replays.
// k_proj_qkg pinned to the r8 config (128 stripes, it=4): r9 (unroll 2,
// VGPR 72->80) and r10 (2x blocks, FETCH 18->30MB) both regressed it.
//
// Fragment layouts (HW-verified):
//   A-frag: lane holds A[m=lane&15][k=(lane>>4)*8+j], j=0..7 (16B)
//   B-frag: lane holds B[k=(lane>>4)*8+j][n=lane&15]
//   D:      lane holds D[row=(lane>>4)*4+reg][col=lane&15]
//
// Workspace (byte offsets):
//   PNb  u16 [65536][128]     @ 0            16,777,216   LN(pair), row p=r*256+sc
//   Qr4  u16 tiled [16384][256][4] @ 16777216 33,554,432  (p>>2, n, p&3), p=(i,sc)
//   Kr4  u16 tiled             @ 50331648    33,554,432
//   Vtb  u16 [8][8192][256]   @ 83886080     33,554,432   [h][k*32+d][j]
//   G2   u16 tiled             @ 117440512   33,554,432   p = r*256+sc (= kslot*256+i)
//   GOb  u16 [65536][256]     @ 150994944    33,554,432   row = i*256+k
//   Bp   f32 [8][256][256]    @ 184549376     2,097,152
//   Ab   u16 [8][256][256]    @ 186646528     1,048,576
//   Wtb  u16 [4][256][128]    @ 187695104       262,144   W{q,k,v,g}^T [n][k]
//   Wotb u16 [128][256]       @ 187957248        65,536   Wo^T [c][e]
//   Lg2  f32 [16][8][256][256]@ 188022784    33,554,432   split-K logit slices
// total 221,577,216 B

typedef unsigned short u16;
typedef __attribute__((ext_vector_type(8))) short short8;
typedef __attribute__((ext_vector_type(4))) short short4v;
typedef __attribute__((ext_vector_type(4))) float float4v;

__device__ __forceinline__ u16 f2bf(float f) {
  unsigned int u = __float_as_uint(f);
  u += 0x7FFFu + ((u >> 16) & 1u);
  return (u16)(u >> 16);
}
__device__ __forceinline__ float bf2f(u16 h) {
  return __uint_as_float(((unsigned int)h) << 16);
}

// ---------------- K1 v2: LayerNorm(pair) -> PNb (bf16) ----------------
// 8 threads/row x 16 elems; 8-lane butterfly stats; two 16B packed stores.
__global__ __launch_bounds__(256) void k_ln(const float* __restrict__ x,
                                            const float* __restrict__ g,
                                            const float* __restrict__ b,
                                            u16* __restrict__ y) {
  const int t = threadIdx.x;
  const int row = t >> 3, h = t & 7;
  const int p = blockIdx.x * 32 + row;
  const float* rp = x + (size_t)p * 128 + h * 16;
  float4 xv[4];
#pragma unroll
  for (int i = 0; i < 4; ++i) xv[i] = ((const float4*)rp)[i];
  float s = 0.f, ss = 0.f;
#pragma unroll
  for (int i = 0; i < 4; ++i) {
    s += (xv[i].x + xv[i].y) + (xv[i].z + xv[i].w);
    ss += (xv[i].x * xv[i].x + xv[i].y * xv[i].y) + (xv[i].z * xv[i].z + xv[i].w * xv[i].w);
  }
#pragma unroll
  for (int off = 1; off <= 4; off <<= 1) {
    s += __shfl_xor(s, off);
    ss += __shfl_xor(ss, off);
  }
  float m = s * (1.0f / 128.0f);
  float var = ss * (1.0f / 128.0f) - m * m;
  float inv = rsqrtf(var + 1e-5f);
  const float4* g4 = (const float4*)(g + h * 16);
  const float4* b4 = (const float4*)(b + h * 16);
  short8 o[2];
#pragma unroll
  for (int i4 = 0; i4 < 4; ++i4) {
    float4 gv = g4[i4], bv = b4[i4];
    o[i4 >> 1][(i4 & 1) * 4 + 0] = (short)f2bf((xv[i4].x - m) * inv * gv.x + bv.x);
    o[i4 >> 1][(i4 & 1) * 4 + 1] = (short)f2bf((xv[i4].y - m) * inv * gv.y + bv.y);
    o[i4 >> 1][(i4 & 1) * 4 + 2] = (short)f2bf((xv[i4].z - m) * inv * gv.z + bv.z);
    o[i4 >> 1][(i4 & 1) * 4 + 3] = (short)f2bf((xv[i4].w - m) * inv * gv.w + bv.w);
  }
  u16* op = y + (size_t)p * 128 + h * 16;
  *(short8*)op = o[0];
  *(short8*)(op + 8) = o[1];
}

// ---------------- K2: LayerNorm(bias) -> Bp (fp32) ----------------
__global__ __launch_bounds__(256) void k_lnbias_bproj(const float* __restrict__ x,
                                                      const float* __restrict__ g,
                                                      const float* __restrict__ b,
                                                      const float* __restrict__ Wb,
                                                      float* __restrict__ Bp) {
  const int t = threadIdx.x;
  const int row = t >> 3, h = t & 7;
  const int p = blockIdx.x * 32 + row;
  const int r = p >> 8, sc = p & 255;
  const float* rp = x + (size_t)p * 128 + h * 16;
  float4 xv[4];
#pragma unroll
  for (int i = 0; i < 4; ++i) xv[i] = ((const float4*)rp)[i];
  float s = 0.f, ss = 0.f;
#pragma unroll
  for (int i = 0; i < 4; ++i) {
    s += (xv[i].x + xv[i].y) + (xv[i].z + xv[i].w);
    ss += (xv[i].x * xv[i].x + xv[i].y * xv[i].y) + (xv[i].z * xv[i].z + xv[i].w * xv[i].w);
  }
#pragma unroll
  for (int off = 1; off <= 4; off <<= 1) {
    s += __shfl_xor(s, off);
    ss += __shfl_xor(ss, off);
  }
  float m = s * (1.0f / 128.0f);
  float var = ss * (1.0f / 128.0f) - m * m;
  float inv = rsqrtf(var + 1e-5f);
  float part[8];
#pragma unroll
  for (int hh = 0; hh < 8; ++hh) part[hh] = 0.f;
  const float4* g4 = (const float4*)(g + h * 16);
  const float4* b4 = (const float4*)(b + h * 16);
#pragma unroll
  for (int i4 = 0; i4 < 4; ++i4) {
    float4 gv = g4[i4], bv = b4[i4];
    float xs[4] = {xv[i4].x, xv[i4].y, xv[i4].z, xv[i4].w};
    float gs[4] = {gv.x, gv.y, gv.z, gv.w};
    float bs[4] = {bv.x, bv.y, bv.z, bv.w};
#pragma unroll
    for (int q = 0; q < 4; ++q) {
      int k = h * 16 + i4 * 4 + q;
      float xn = (xs[q] - m) * inv * gs[q] + bs[q];
      float4 w0 = *(const float4*)(Wb + k * 8);
      float4 w1 = *(const float4*)(Wb + k * 8 + 4);
      part[0] += xn * w0.x;
      part[1] += xn * w0.y;
      part[2] += xn * w0.z;
      part[3] += xn * w0.w;
      part[4] += xn * w1.x;
      part[5] += xn * w1.y;
      part[6] += xn * w1.z;
      part[7] += xn * w1.w;
    }
  }
#pragma unroll
  for (int off = 1; off <= 4; off <<= 1) {
#pragma unroll
    for (int hh = 0; hh < 8; ++hh) part[hh] += __shfl_xor(part[hh], off);
  }
  float val = (h == 0) ? part[0]
            : (h == 1) ? part[1]
            : (h == 2) ? part[2]
            : (h == 3) ? part[3]
            : (h == 4) ? part[4]
            : (h == 5) ? part[5]
            : (h == 6) ? part[6]
                       : part[7];
  Bp[(size_t)h * 65536 + (size_t)sc * 256 + r] = val;
}

// ---------------- K3: weight convert/transpose to bf16 ----------------
__global__ __launch_bounds__(256) void k_wcvt(const float* __restrict__ Wq,
                                              const float* __restrict__ Wk,
                                              const float* __restrict__ Wv,
                                              const float* __restrict__ Wg,
                                              const float* __restrict__ Wo,
                                              u16* __restrict__ Wtb,
                                              u16* __restrict__ Wotb) {
  int idx = blockIdx.x * 256 + threadIdx.x;
  if (idx < 131072) {
    int w = idx >> 15, r = idx & 32767;
    int n = r >> 7, k = r & 127;  // out [n][k]
    const float* W = (w == 0) ? Wq : (w == 1) ? Wk : (w == 2) ? Wv : Wg;
    Wtb[(size_t)w * 32768 + n * 128 + k] = f2bf(W[k * 256 + n]);
  } else {
    int r = idx - 131072;  // Wo [256 e][128 c] -> Wotb[c][e]
    int c = r >> 8, e = r & 255;
    Wotb[c * 256 + e] = f2bf(Wo[e * 128 + c]);
  }
}

// ---------------- K4 (r8 config): Q/K/gate projections, tiled packed stores --
// grid (128 stripes of 512 rows, 4 col-quarters, 3 weights). No LDS/barriers.
__global__ __launch_bounds__(256) void k_proj_qkg(const u16* __restrict__ PNb,
                                                  const u16* __restrict__ Wtb,
                                                  const float* __restrict__ bg,
                                                  u16* __restrict__ Qr4,
                                                  u16* __restrict__ Kr4,
                                                  u16* __restrict__ G2) {
  const int t = threadIdx.x;
  const int wid = t >> 6, lane = t & 63;
  const int mrow = lane & 15, quad = lane >> 4;
  const int stripe = blockIdx.x;
  const int n0 = blockIdx.y * 64;
  const int wsel3 = blockIdx.z;  // 0:Q 1:K 2:G
  const int wsel = (wsel3 == 2) ? 3 : wsel3;
  const u16* Wt = Wtb + (size_t)wsel * 32768;
  u16* dst = (wsel3 == 0) ? Qr4 : (wsel3 == 1) ? Kr4 : G2;

  short8 bfr[4][4];
#pragma unroll
  for (int nt = 0; nt < 4; ++nt)
#pragma unroll
    for (int kk = 0; kk < 4; ++kk)
      bfr[nt][kk] = *(const short8*)(Wt + (size_t)(n0 + nt * 16 + mrow) * 128 + kk * 32 + quad * 8);

  float bgv[4];
#pragma unroll
  for (int nt = 0; nt < 4; ++nt) bgv[nt] = bg[n0 + nt * 16 + mrow];

  for (int it = 0; it < 4; ++it) {
    const int pw = stripe * 512 + it * 128 + wid * 32;
    short8 afr[2][4];
#pragma unroll
    for (int mt = 0; mt < 2; ++mt)
#pragma unroll
      for (int kk = 0; kk < 4; ++kk)
        afr[mt][kk] =
            *(const short8*)(PNb + (size_t)(pw + mt * 16 + mrow) * 128 + kk * 32 + quad * 8);
    float4v acc[2][4];
#pragma unroll
    for (int mt = 0; mt < 2; ++mt)
#pragma unroll
      for (int nt = 0; nt < 4; ++nt) acc[mt][nt] = (float4v){0.f, 0.f, 0.f, 0.f};
#pragma unroll
    for (int kk = 0; kk < 4; ++kk)
#pragma unroll
      for (int mt = 0; mt < 2; ++mt)
#pragma unroll
        for (int nt = 0; nt < 4; ++nt)
          acc[mt][nt] = __builtin_amdgcn_mfma_f32_16x16x32_bf16(afr[mt][kk], bfr[nt][kk],
                                                                acc[mt][nt], 0, 0, 0);
#pragma unroll
    for (int mt = 0; mt < 2; ++mt) {
      const int prow4 = ((pw + mt * 16) >> 2) + quad;  // p>>2 for this lane's 4 rows
#pragma unroll
      for (int nt = 0; nt < 4; ++nt) {
        const int n = n0 + nt * 16 + mrow;
        short4v pk;
#pragma unroll
        for (int reg = 0; reg < 4; ++reg) {
          float v = acc[mt][nt][reg];
          if (wsel3 == 0) v *= 0.17677669529663687f;
          else if (wsel3 == 1) v *= 0.0625f;
          else v = 1.f / (1.f + expf(-(v + bgv[nt])));
          pk[reg] = (short)f2bf(v);
        }
        *(short4v*)(dst + ((size_t)prow4 * 256 + n) * 4) = pk;
      }
    }
  }
}

// ---------------- K5 v2: V projection, direct packed stores into Vtb --------
__global__ __launch_bounds__(256) void k_projv(const u16* __restrict__ PNb,
                                               const u16* __restrict__ Wtb,
                                               u16* __restrict__ Vtb) {
  const int t = threadIdx.x;
  const int wid = t >> 6, lane = t & 63;
  const int mrow = lane & 15, quad = lane >> 4;
  const int sc = blockIdx.x;
  const int n0 = blockIdx.y * 64;
  const u16* Wt = Wtb + (size_t)2 * 32768;

  short8 bfr[4][4];
#pragma unroll
  for (int nt = 0; nt < 4; ++nt)
#pragma unroll
    for (int kk = 0; kk < 4; ++kk)
      bfr[nt][kk] = *(const short8*)(Wt + (size_t)(n0 + nt * 16 + mrow) * 128 + kk * 32 + quad * 8);

  for (int it = 0; it < 2; ++it) {
    const int rbase = it * 128 + wid * 32;
    short8 afr[2][4];
#pragma unroll
    for (int mt = 0; mt < 2; ++mt)
#pragma unroll
      for (int kk = 0; kk < 4; ++kk)
        afr[mt][kk] = *(const short8*)(PNb + ((size_t)(rbase + mt * 16 + mrow) * 256 + sc) * 128 +
                                       kk * 32 + quad * 8);
    float4v acc[2][4];
#pragma unroll
    for (int mt = 0; mt < 2; ++mt)
#pragma unroll
      for (int nt = 0; nt < 4; ++nt) acc[mt][nt] = (float4v){0.f, 0.f, 0.f, 0.f};
#pragma unroll
    for (int kk = 0; kk < 4; ++kk)
#pragma unroll
      for (int mt = 0; mt < 2; ++mt)
#pragma unroll
        for (int nt = 0; nt < 4; ++nt)
          acc[mt][nt] = __builtin_amdgcn_mfma_f32_16x16x32_bf16(afr[mt][kk], bfr[nt][kk],
                                                                acc[mt][nt], 0, 0, 0);
#pragma unroll
    for (int mt = 0; mt < 2; ++mt) {
      const int j0 = rbase + mt * 16 + quad * 4;  // 4 consecutive j
#pragma unroll
      for (int nt = 0; nt < 4; ++nt) {
        const int n = n0 + nt * 16 + mrow;
        const int h = n >> 5, d = n & 31;
        short4v pk;
#pragma unroll
        for (int reg = 0; reg < 4; ++reg) pk[reg] = (short)f2bf(acc[mt][nt][reg]);
        *(short4v*)(Vtb + (size_t)h * 2097152 + (size_t)(sc * 32 + d) * 256 + j0) = pk;
      }
    }
  }
}

// ---------------- K6 v2: logits (MFMA) from tiled Qr4/Kr4 ----------------
__global__ __launch_bounds__(256) void k_logits_mfma(const u16* __restrict__ Qr4,
                                                     const u16* __restrict__ Kr4,
                                                     float* __restrict__ Lg2) {
  __shared__ u16 Qs[128 * 72];
  __shared__ u16 Ks[128 * 72];
  const int t = threadIdx.x;
  const int wid = t >> 6, lane = t & 63;
  const int mrow = lane & 15, quad = lane >> 4;
  const int i0 = (blockIdx.x >> 1) * 128, j0 = (blockIdx.x & 1) * 128;
  const int h = blockIdx.y;
  const int z = blockIdx.z;  // 0..15
  const int wi = wid >> 1, wj = wid & 1;
  float4v acc[4][4];
#pragma unroll
  for (int a = 0; a < 4; ++a)
#pragma unroll
    for (int bq = 0; bq < 4; ++bq) acc[a][bq] = (float4v){0.f, 0.f, 0.f, 0.f};

  for (int g = 0; g < 4; ++g) {
    const int sc4 = z * 4 + g;
    for (int sub = 0; sub < 2; ++sub) {
      __syncthreads();
#pragma unroll
      for (int itq = 0; itq < 4; ++itq) {
        int u = itq * 256 + t;
        int i_loc = u >> 3, c16 = sub * 8 + (u & 7);
        size_t qoff = ((size_t)((i0 + i_loc) * 64 + sc4) * 256 + h * 32 + c16 * 2) * 4;
        *(short8*)&Qs[i_loc * 72 + (u & 7) * 8] = *(const short8*)(Qr4 + qoff);
        size_t koff = ((size_t)((j0 + i_loc) * 64 + sc4) * 256 + h * 32 + c16 * 2) * 4;
        *(short8*)&Ks[i_loc * 72 + (u & 7) * 8] = *(const short8*)(Kr4 + koff);
      }
      __syncthreads();
#pragma unroll
      for (int kk = 0; kk < 2; ++kk) {
        short8 afr[4], bfr[4];
#pragma unroll
        for (int mt = 0; mt < 4; ++mt)
          afr[mt] = *(const short8*)&Qs[(wi * 64 + mt * 16 + mrow) * 72 + kk * 32 + quad * 8];
#pragma unroll
        for (int nn = 0; nn < 4; ++nn)
          bfr[nn] = *(const short8*)&Ks[(wj * 64 + nn * 16 + mrow) * 72 + kk * 32 + quad * 8];
#pragma unroll
        for (int mt = 0; mt < 4; ++mt)
#pragma unroll
          for (int nn = 0; nn < 4; ++nn)
            acc[mt][nn] =
                __builtin_amdgcn_mfma_f32_16x16x32_bf16(afr[mt], bfr[nn], acc[mt][nn], 0, 0, 0);
      }
    }
  }
  float* slab = Lg2 + ((size_t)z * 8 + h) * 65536;
#pragma unroll
  for (int mt = 0; mt < 4; ++mt)
#pragma unroll
    for (int nn = 0; nn < 4; ++nn) {
      int j = j0 + wj * 64 + nn * 16 + mrow;
#pragma unroll
      for (int reg = 0; reg < 4; ++reg) {
        int i = i0 + wi * 64 + mt * 16 + quad * 4 + reg;
        slab[(size_t)i * 256 + j] = acc[mt][nn][reg];
      }
    }
}

// ---------------- K7: masked softmax over j (sum Bp + 16 slabs) -> Ab --------
__global__ __launch_bounds__(256) void k_softmax(const float* __restrict__ Bp,
                                                 const float* __restrict__ Lg2,
                                                 const int* __restrict__ mask,
                                                 u16* __restrict__ Ab) {
  const int i = blockIdx.x, h = blockIdx.y;
  const int j = threadIdx.x;
  __shared__ float red[4], red2[4];
  const size_t off = (size_t)h * 65536 + (size_t)i * 256 + j;
  float x = Bp[off];
#pragma unroll
  for (int z = 0; z < 16; ++z) x += Lg2[(size_t)z * 524288 + off];
  bool mi = (mask[i] == 0);
  if (mi || (mask[j] == 0)) x = -1e9f;
  float mx = x;
#pragma unroll
  for (int off2 = 32; off2; off2 >>= 1) mx = fmaxf(mx, __shfl_xor(mx, off2));
  int wave = j >> 6;
  if ((j & 63) == 0) red[wave] = mx;
  __syncthreads();
  mx = fmaxf(fmaxf(red[0], red[1]), fmaxf(red[2], red[3]));
  float e = expf(x - mx);
  float sm = e;
#pragma unroll
  for (int off2 = 32; off2; off2 >>= 1) sm += __shfl_xor(sm, off2);
  if ((j & 63) == 0) red2[wave] = sm;
  __syncthreads();
  sm = red2[0] + red2[1] + red2[2] + red2[3];
  Ab[off] = f2bf(e / sm);
}

// ---------------- K8: AV (MFMA) + gate (b64 tiled loads) -> GOb --------------
__global__ __launch_bounds__(256) void k_av_mfma(const u16* __restrict__ Ab,
                                                 const u16* __restrict__ Vtb,
                                                 const u16* __restrict__ G2,
                                                 u16* __restrict__ GOb) {
  __shared__ u16 As[64 * 264];
  const int t = threadIdx.x;
  const int wid = t >> 6, lane = t & 63;
  const int mrow = lane & 15, quad = lane >> 4;
  const int h = blockIdx.z;
  const int i0 = blockIdx.y * 64;
  const u16* ag = Ab + (size_t)h * 65536 + (size_t)i0 * 256;
#pragma unroll
  for (int u = 0; u < 8; ++u) {
    int id = u * 256 + t;
    int rr = id >> 5, c8 = (id & 31) * 8;
    *(short8*)&As[rr * 264 + c8] = *(const short8*)(ag + (size_t)rr * 256 + c8);
  }
  __syncthreads();
  const u16* vg = Vtb + (size_t)h * 2097152;
  for (int nt4 = 0; nt4 < 4; ++nt4) {
    const int nbase = blockIdx.x * 1024 + wid * 256 + nt4 * 64;
    float4v acc[4][4];
#pragma unroll
    for (int a = 0; a < 4; ++a)
#pragma unroll
      for (int bq = 0; bq < 4; ++bq) acc[a][bq] = (float4v){0.f, 0.f, 0.f, 0.f};
#pragma unroll
    for (int kk = 0; kk < 8; ++kk) {
      short8 afr[4], bfr[4];
#pragma unroll
      for (int mt = 0; mt < 4; ++mt)
        afr[mt] = *(const short8*)&As[(mt * 16 + mrow) * 264 + kk * 32 + quad * 8];
#pragma unroll
      for (int nn = 0; nn < 4; ++nn)
        bfr[nn] = *(const short8*)(vg + (size_t)(nbase + nn * 16 + mrow) * 256 + kk * 32 + quad * 8);
#pragma unroll
      for (int mt = 0; mt < 4; ++mt)
#pragma unroll
        for (int nn = 0; nn < 4; ++nn)
          acc[mt][nn] = __builtin_amdgcn_mfma_f32_16x16x32_bf16(afr[mt], bfr[nn], acc[mt][nn], 0, 0, 0);
    }
#pragma unroll
    for (int mt = 0; mt < 4; ++mt)
#pragma unroll
      for (int nn = 0; nn < 4; ++nn) {
        const int kslot = (nbase + nn * 16) >> 5;
        const int d = (nn & 1) * 16 + mrow;
        const int e = h * 32 + d;
        const int p4 = kslot * 64 + ((i0 + mt * 16) >> 2) + quad;
        short4v g4 = *(const short4v*)(G2 + ((size_t)p4 * 256 + e) * 4);
#pragma unroll
        for (int reg = 0; reg < 4; ++reg) {
          int i = i0 + mt * 16 + quad * 4 + reg;
          size_t idx = ((size_t)i * 256 + kslot) * 256 + e;
          float gv = bf2f((u16)g4[reg]);
          GOb[idx] = f2bf(acc[mt][nn][reg] * gv);
        }
      }
  }
}

// ---------------- K9: output proj (MFMA) + bias + transpose + mask ----------------
__global__ __launch_bounds__(256) void k_out_mfma(const u16* __restrict__ GOb,
                                                  const u16* __restrict__ Wotb,
                                                  const float* __restrict__ bo,
                                                  const int* __restrict__ mask,
                                                  float* __restrict__ out) {
  const int wid = threadIdx.x >> 6, lane = threadIdx.x & 63;
  const int mrow = lane & 15, quad = lane >> 4;
  const int m0 = blockIdx.x * 128 + wid * 32;
  short8 afr[2][8];
#pragma unroll
  for (int mt = 0; mt < 2; ++mt) {
    const u16* ar = GOb + (size_t)(m0 + mt * 16 + mrow) * 256 + quad * 8;
#pragma unroll
    for (int kk = 0; kk < 8; ++kk) afr[mt][kk] = *(const short8*)(ar + kk * 32);
  }
  for (int nt = 0; nt < 8; ++nt) {
    float4v acc[2];
    acc[0] = (float4v){0.f, 0.f, 0.f, 0.f};
    acc[1] = (float4v){0.f, 0.f, 0.f, 0.f};
    const u16* br = Wotb + (size_t)(nt * 16 + mrow) * 256 + quad * 8;
#pragma unroll
    for (int kk = 0; kk < 8; ++kk) {
      short8 bfr = *(const short8*)(br + kk * 32);
#pragma unroll
      for (int mt = 0; mt < 2; ++mt)
        acc[mt] = __builtin_amdgcn_mfma_f32_16x16x32_bf16(afr[mt][kk], bfr, acc[mt], 0, 0, 0);
    }
    const int c = nt * 16 + mrow;
    float bov = bo[c];
#pragma unroll
    for (int mt = 0; mt < 2; ++mt) {
#pragma unroll
      for (int reg = 0; reg < 4; ++reg) {
        int m = m0 + mt * 16 + quad * 4 + reg;  // = i*256 + k
        int i = m >> 8, kq = m & 255;
        float v = acc[mt][reg] + bov;
        bool z = (mask[i] == 0) || (mask[kq] == 0);
        out[((size_t)kq * 256 + i) * 128 + c] = z ? 0.f : v;
      }
    }
  }
}

extern "C" void kernel_launch(void* const* d_in, const int* in_sizes, int n_in,
                              void* d_out, int out_size, void* d_ws, size_t ws_size,
                              hipStream_t stream) {
  const float* pair = (const float*)d_in[0];
  const float* bias = (const float*)d_in[1];
  const int* mask = (const int*)d_in[2];
  const float* g_pair = (const float*)d_in[3];
  const float* b_pair = (const float*)d_in[4];
  const float* g_bias = (const float*)d_in[5];
  const float* b_bias = (const float*)d_in[6];
  const float* Wq = (const float*)d_in[7];
  const float* Wk = (const float*)d_in[8];
  const float* Wv = (const float*)d_in[9];
  const float* Wb = (const float*)d_in[10];
  const float* Wg = (const float*)d_in[11];
  const float* bg = (const float*)d_in[12];
  const float* Wo = (const float*)d_in[13];
  const float* bo = (const float*)d_in[14];
  float* out = (float*)d_out;
  char* ws = (char*)d_ws;

  u16* PNb = (u16*)(ws + 0);
  u16* Qr4 = (u16*)(ws + 16777216);
  u16* Kr4 = (u16*)(ws + 50331648);
  u16* Vtb = (u16*)(ws + 83886080);
  u16* G2 = (u16*)(ws + 117440512);
  u16* GOb = (u16*)(ws + 150994944);
  float* Bp = (float*)(ws + 184549376);
  u16* Ab = (u16*)(ws + 186646528);
  u16* Wtb = (u16*)(ws + 187695104);
  u16* Wotb = (u16*)(ws + 187957248);
  float* Lg2 = (float*)(ws + 188022784);

  k_ln<<<2048, 256, 0, stream>>>(pair, g_pair, b_pair, PNb);
  k_wcvt<<<640, 256, 0, stream>>>(Wq, Wk, Wv, Wg, Wo, Wtb, Wotb);
  k_lnbias_bproj<<<2048, 256, 0, stream>>>(bias, g_bias, b_bias, Wb, Bp);
  k_proj_qkg<<<dim3(128, 4, 3), 256, 0, stream>>>(PNb, Wtb, bg, Qr4, Kr4, G2);
  k_projv<<<dim3(256, 4), 256, 0, stream>>>(PNb, Wtb, Vtb);
  k_logits_mfma<<<dim3(4, 8, 16), 256, 0, stream>>>(Qr4, Kr4, Lg2);
  k_softmax<<<dim3(256, 8), 256, 0, stream>>>(Bp, Lg2, mask, Ab);
  k_av_mfma<<<dim3(8, 4, 8), 256, 0, stream>>>(Ab, Vtb, G2, GOb);
  k_out_mfma<<<512, 256, 0, stream>>>(GOb, Wotb, bo, mask, out);
}